// Round 5
// baseline (245.457 us; speedup 1.0000x reference)
//
#include <hip/hip_runtime.h>

#define DM 128
#define DFF 512
#define CLAMP_V 5.0f
#define LN_EPS 1e-5f

typedef __attribute__((ext_vector_type(8))) short bf16x8;
typedef __attribute__((ext_vector_type(4))) float f32x4;

__device__ __forceinline__ float b2f(ushort u) {
  union { uint u; float f; } x; x.u = ((uint)u) << 16; return x.f;
}
__device__ __forceinline__ ushort f2b(float f) {
  union { float f; uint u; } x; x.f = f;
  uint r = x.u + 0x7FFFu + ((x.u >> 16) & 1u);
  return (ushort)(r >> 16);
}
// 1-inst-per-element bf16 pair unpack
__device__ __forceinline__ void unpackw(uint w, float& lo, float& hi) {
  union { uint u; float f; } A, B;
  A.u = w << 16; B.u = w & 0xFFFF0000u;
  lo = A.f; hi = B.f;
}
__device__ __forceinline__ void unpack8w(uint4 w, float* o) {
  unpackw(w.x, o[0], o[1]); unpackw(w.y, o[2], o[3]);
  unpackw(w.z, o[4], o[5]); unpackw(w.w, o[6], o[7]);
}

// ---------------- casts ----------------
__global__ void k_cast(const float* __restrict__ s, ushort* __restrict__ d, int n) {
  int i4 = (blockIdx.x * blockDim.x + threadIdx.x) * 4;
  if (i4 + 3 < n) {
    float4 v = *reinterpret_cast<const float4*>(s + i4);
    ushort4 o; o.x = f2b(v.x); o.y = f2b(v.y); o.z = f2b(v.z); o.w = f2b(v.w);
    *reinterpret_cast<ushort4*>(d + i4) = o;
  } else {
    for (; i4 < n; ++i4) d[i4] = f2b(s[i4]);
  }
}

__global__ void k_castw(const float* __restrict__ wq, const float* __restrict__ wk,
                        const float* __restrict__ wv, const float* __restrict__ wo,
                        const float* __restrict__ w1, const float* __restrict__ w2,
                        ushort* __restrict__ d) {
  int i4 = (blockIdx.x * blockDim.x + threadIdx.x) * 4;
  if (i4 >= 196608) return;
  const float* s; int o;
  if      (i4 < 16384)  { s = wq; o = i4; }
  else if (i4 < 32768)  { s = wk; o = i4 - 16384; }
  else if (i4 < 49152)  { s = wv; o = i4 - 32768; }
  else if (i4 < 65536)  { s = wo; o = i4 - 49152; }
  else if (i4 < 131072) { s = w1; o = i4 - 65536; }
  else                  { s = w2; o = i4 - 131072; }
  float4 v = *reinterpret_cast<const float4*>(s + o);
  ushort4 u; u.x = f2b(v.x); u.y = f2b(v.y); u.z = f2b(v.z); u.w = f2b(v.w);
  *reinterpret_cast<ushort4*>(d + i4) = u;
}

// ---------------- CSR build ----------------
__global__ void k_count(const int* __restrict__ dst, int* __restrict__ deg, int E) {
  int e = blockIdx.x * blockDim.x + threadIdx.x;
  if (e < E) atomicAdd(&deg[dst[e]], 1);
}

#define SC_EPB 1024

__global__ __launch_bounds__(256) void k_scan1(const int* __restrict__ deg,
                                               int* __restrict__ off,
                                               int* __restrict__ bsum, int n) {
  __shared__ int sh[256];
  const int t = threadIdx.x;
  int base = blockIdx.x * SC_EPB + t * 4;
  int4 v = {0, 0, 0, 0};
  if (base + 3 < n) {
    v = *reinterpret_cast<const int4*>(deg + base);
  } else {
    if (base     < n) v.x = deg[base];
    if (base + 1 < n) v.y = deg[base + 1];
    if (base + 2 < n) v.z = deg[base + 2];
    if (base + 3 < n) v.w = deg[base + 3];
  }
  int s = v.x + v.y + v.z + v.w;
  sh[t] = s;
  __syncthreads();
  #pragma unroll
  for (int d = 1; d < 256; d <<= 1) {
    int x = 0;
    if (t >= d) x = sh[t - d];
    __syncthreads();
    sh[t] += x;
    __syncthreads();
  }
  int ex = sh[t] - s;
  if (base + 3 < n) {
    int4 o; o.x = ex; o.y = ex + v.x; o.z = ex + v.x + v.y; o.w = ex + v.x + v.y + v.z;
    *reinterpret_cast<int4*>(off + base) = o;
  } else {
    if (base     < n) off[base]     = ex;
    if (base + 1 < n) off[base + 1] = ex + v.x;
    if (base + 2 < n) off[base + 2] = ex + v.x + v.y;
    if (base + 3 < n) off[base + 3] = ex + v.x + v.y + v.z;
  }
  if (t == 255) bsum[blockIdx.x] = sh[255];
}

__global__ __launch_bounds__(256) void k_scan2(int* __restrict__ bsum, int nb) {
  __shared__ int sh[256];
  const int t = threadIdx.x;
  int v = (t < nb) ? bsum[t] : 0;
  sh[t] = v;
  __syncthreads();
  #pragma unroll
  for (int d = 1; d < 256; d <<= 1) {
    int x = 0;
    if (t >= d) x = sh[t - d];
    __syncthreads();
    sh[t] += x;
    __syncthreads();
  }
  if (t < nb) bsum[t] = sh[t] - v;
}

__global__ __launch_bounds__(256) void k_scan3(int* __restrict__ off,
                                               const int* __restrict__ bsum,
                                               int n, int E) {
  int add = bsum[blockIdx.x];
  int base = blockIdx.x * SC_EPB + threadIdx.x * 4;
  if (base + 3 < n) {
    int4 v = *reinterpret_cast<int4*>(off + base);
    v.x += add; v.y += add; v.z += add; v.w += add;
    *reinterpret_cast<int4*>(off + base) = v;
  } else {
    if (base     < n) off[base]     += add;
    if (base + 1 < n) off[base + 1] += add;
    if (base + 2 < n) off[base + 2] += add;
  }
  if (blockIdx.x == 0 && threadIdx.x == 0) off[n] = E;
}

__global__ void k_scatter(const int* __restrict__ src, const int* __restrict__ dst,
                          const int* __restrict__ off, int* __restrict__ cur,
                          int* __restrict__ csr, int E) {
  int e = blockIdx.x * blockDim.x + threadIdx.x;
  if (e < E) {
    int d = dst[e];
    int p = off[d] + atomicAdd(&cur[d], 1);
    csr[p] = src[e];
  }
}

// ---------------- bf16 MFMA GEMM, optional fused LayerNorm epilogue ----------------
// FLAGS: 1=bias 2=relu 4=residual 8=fused-LN (requires NO==BN==128, bn==0)
#define BM 128
#define BN 128
#define BK 64
#define LNP 132   // LN tile leading dim (132%32=4 -> 2-way LDS conflicts, free)

template<int FLAGS, bool OUTF, bool OUTB>
__global__ __launch_bounds__(256, 2) void k_mm(
    const ushort* __restrict__ A, const ushort* __restrict__ W,
    const float* __restrict__ bias, const float* __restrict__ res,
    const float* __restrict__ lng, const float* __restrict__ lnbv,
    float* __restrict__ Cf, ushort* __restrict__ Cb,
    int M, int NO, int K)
{
  constexpr int SMEM_BYTES = (FLAGS & 8) ? (BM * LNP * 4) : (BM * BK * 2 + BN * BK * 2);
  __shared__ __align__(16) char smem[SMEM_BYTES];
  ushort* As = (ushort*)smem;
  ushort* Ws = (ushort*)(smem + BM * BK * 2);

  const int tid = threadIdx.x;
  const int wv = tid >> 6, ln = tid & 63;
  const int bm = blockIdx.y * BM, bn = blockIdx.x * BN;
  const int wrow = (wv >> 1) * 64, wcol = (wv & 1) * 64;

  f32x4 acc[4][4] = {};
  const int o_base = wv * 1024 + ln * 16;

  for (int k0 = 0; k0 < K; k0 += BK) {
    #pragma unroll
    for (int is = 0; is < 4; ++is) {
      int o = is * 4096 + o_base;
      int row = o >> 7;
      int c = ((o >> 4) & 7) ^ (row & 7);
      int gm = bm + row; if (gm >= M) gm = M - 1;
      const ushort* srcA = A + (size_t)gm * K + k0 + c * 8;
      __builtin_amdgcn_global_load_lds(
          (const __attribute__((address_space(1))) void*)srcA,
          (__attribute__((address_space(3))) void*)((char*)As + is * 4096 + wv * 1024),
          16, 0, 0);
      int gn = bn + row;
      const ushort* srcW = W + (size_t)gn * K + k0 + c * 8;
      __builtin_amdgcn_global_load_lds(
          (const __attribute__((address_space(1))) void*)srcW,
          (__attribute__((address_space(3))) void*)((char*)Ws + is * 4096 + wv * 1024),
          16, 0, 0);
    }
    __syncthreads();

    const char* AsB = (const char*)As;
    const char* WsB = (const char*)Ws;
    #pragma unroll
    for (int kk = 0; kk < 2; ++kk) {
      bf16x8 af[4], bf[4];
      #pragma unroll
      for (int m = 0; m < 4; ++m) {
        int r = wrow + m * 16 + (ln & 15);
        int c = kk * 4 + (ln >> 4);
        af[m] = *reinterpret_cast<const bf16x8*>(AsB + r * 128 + ((c ^ (r & 7)) << 4));
      }
      #pragma unroll
      for (int n = 0; n < 4; ++n) {
        int r = wcol + n * 16 + (ln & 15);
        int c = kk * 4 + (ln >> 4);
        bf[n] = *reinterpret_cast<const bf16x8*>(WsB + r * 128 + ((c ^ (r & 7)) << 4));
      }
      #pragma unroll
      for (int m = 0; m < 4; ++m)
        #pragma unroll
        for (int n = 0; n < 4; ++n)
          acc[m][n] = __builtin_amdgcn_mfma_f32_16x16x32_bf16(af[m], bf[n], acc[m][n], 0, 0, 0);
    }
    __syncthreads();
  }

  if constexpr ((FLAGS & 8) != 0) {
    // ---- fused LayerNorm epilogue: NO == BN == 128, bn == 0 ----
    float* L = (float*)smem;
    #pragma unroll
    for (int m = 0; m < 4; ++m) {
      int row0 = wrow + m * 16 + (ln >> 4) * 4;
      #pragma unroll
      for (int n = 0; n < 4; ++n) {
        int col = wcol + n * 16 + (ln & 15);
        float bsv = (FLAGS & 1) ? bias[col] : 0.f;
        #pragma unroll
        for (int r = 0; r < 4; ++r) {
          int row = row0 + r;
          int gr = bm + row;
          float v = acc[m][n][r] + bsv;
          if (FLAGS & 2) v = fmaxf(v, 0.f);
          if ((FLAGS & 4) && gr < M) v += res[(size_t)gr * 128 + col];
          L[row * LNP + col] = v;
        }
      }
    }
    __syncthreads();
    float g0 = lng[2 * ln], g1 = lng[2 * ln + 1];
    float bb0 = lnbv[2 * ln], bb1 = lnbv[2 * ln + 1];
    for (int rr = 0; rr < 32; ++rr) {
      int row = wv * 32 + rr;
      int gr = bm + row;
      if (gr >= M) continue;   // wave-uniform
      float2 x = *reinterpret_cast<float2*>(&L[row * LNP + 2 * ln]);
      float sum = x.x + x.y;
      #pragma unroll
      for (int msk = 1; msk < 64; msk <<= 1) sum += __shfl_xor(sum, msk);
      float mu = sum * (1.f / 128.f);
      float d0 = x.x - mu, d1 = x.y - mu;
      float vs = d0 * d0 + d1 * d1;
      #pragma unroll
      for (int msk = 1; msk < 64; msk <<= 1) vs += __shfl_xor(vs, msk);
      float rstd = rsqrtf(vs * (1.f / 128.f) + LN_EPS);
      float y0 = d0 * rstd * g0 + bb0;
      float y1 = d1 * rstd * g1 + bb1;
      if (OUTF) {
        float2 o = {y0, y1};
        *reinterpret_cast<float2*>(&Cf[(size_t)gr * 128 + 2 * ln]) = o;
      }
      if (OUTB) {
        ushort2 o; o.x = f2b(y0); o.y = f2b(y1);
        *reinterpret_cast<ushort2*>(&Cb[(size_t)gr * 128 + 2 * ln]) = o;
      }
    }
  } else {
    #pragma unroll
    for (int m = 0; m < 4; ++m) {
      int gr0 = bm + wrow + m * 16 + (ln >> 4) * 4;
      #pragma unroll
      for (int n = 0; n < 4; ++n) {
        int gc = bn + wcol + n * 16 + (ln & 15);
        float bsv = (FLAGS & 1) ? bias[gc] : 0.f;
        #pragma unroll
        for (int r = 0; r < 4; ++r) {
          int gr = gr0 + r;
          if (gr >= M) continue;
          float v = acc[m][n][r] + bsv;
          if (FLAGS & 2) v = fmaxf(v, 0.f);
          if (FLAGS & 4) v += res[(size_t)gr * NO + gc];
          if (OUTF) Cf[(size_t)gr * NO + gc] = v;
          if (OUTB) Cb[(size_t)gr * NO + gc] = f2b(v);
        }
      }
    }
  }
}

// ---------------- edge-softmax attention: 8 groups x 8 lanes, lane = full head ----
// q: [N x 128] bf16; kv: [N x 256] bf16 (K at 0, V at +128). Group g handles
// edges b+8i+g; lane sl holds head sl (dims 16sl..16sl+16). Per-group online
// softmax; 3-round butterfly merge (masks 8,16,32).
__global__ __launch_bounds__(256) void k_attn(
    const ushort* __restrict__ q, const ushort* __restrict__ kv,
    const int* __restrict__ off, const int* __restrict__ csr,
    ushort* __restrict__ sav, int n)
{
  int node = blockIdx.x * 4 + (threadIdx.x >> 6);
  int lane = threadIdx.x & 63;
  if (node >= n) return;
  const int g = lane >> 3, sl = lane & 7;

  const ushort* qr = q + (size_t)node * 128 + sl * 16;
  uint4 qw0 = *reinterpret_cast<const uint4*>(qr);
  uint4 qw1 = *reinterpret_cast<const uint4*>(qr + 8);
  float qv[16];
  unpack8w(qw0, qv); unpack8w(qw1, qv + 8);

  int b = off[node], e = off[node + 1];
  float m = -1e30f, s = 0.f;
  float a[16] = {};
  int nIt = (e - b + 7) >> 3;
  int idx = b + g;
  int sn = (b < e) ? csr[min(idx, e - 1)] : 0;

  for (int i = 0; i < nIt; ++i) {
    bool act = idx < e;
    const ushort* kr = kv + (size_t)sn * 256 + sl * 16;
    uint4 kw0 = *reinterpret_cast<const uint4*>(kr);
    uint4 kw1 = *reinterpret_cast<const uint4*>(kr + 8);
    uint4 vw0 = *reinterpret_cast<const uint4*>(kr + 128);
    uint4 vw1 = *reinterpret_cast<const uint4*>(kr + 136);
    idx += 8;
    if (i + 1 < nIt) sn = csr[min(idx, e - 1)];

    float kk[16];
    unpack8w(kw0, kk); unpack8w(kw1, kk + 8);
    float p = 0.f;
    #pragma unroll
    for (int j = 0; j < 16; ++j) p = fmaf(qv[j], kk[j], p);
    float u = fminf(fmaxf(p * 0.25f, -CLAMP_V), CLAMP_V);
    if (act) {
      float mn = fmaxf(m, u);
      float f = __expf(m - mn);
      float w = __expf(u - mn);
      s = s * f + w;
      float vvv[16];
      unpack8w(vw0, vvv); unpack8w(vw1, vvv + 8);
      #pragma unroll
      for (int j = 0; j < 16; ++j) a[j] = a[j] * f + w * vvv[j];
      m = mn;
    }
  }

  #pragma unroll
  for (int msk = 8; msk <= 32; msk <<= 1) {
    float mo = __shfl_xor(m, msk);
    float so = __shfl_xor(s, msk);
    float ao[16];
    #pragma unroll
    for (int j = 0; j < 16; ++j) ao[j] = __shfl_xor(a[j], msk);
    float mn = fmaxf(m, mo);
    float f1 = __expf(m - mn), f2 = __expf(mo - mn);
    s = s * f1 + so * f2;
    #pragma unroll
    for (int j = 0; j < 16; ++j) a[j] = a[j] * f1 + ao[j] * f2;
    m = mn;
  }

  float inv = (s > 0.f) ? 1.f / s : 0.f;
  if (g == 0) {
    uint w[8];
    #pragma unroll
    for (int j = 0; j < 8; ++j)
      w[j] = (uint)f2b(a[2 * j] * inv) | ((uint)f2b(a[2 * j + 1] * inv) << 16);
    ushort* outp = sav + (size_t)node * 128 + sl * 16;
    uint4 o0 = {w[0], w[1], w[2], w[3]};
    uint4 o1 = {w[4], w[5], w[6], w[7]};
    *reinterpret_cast<uint4*>(outp) = o0;
    *reinterpret_cast<uint4*>(outp + 8) = o1;
  }
}

extern "C" void kernel_launch(void* const* d_in, const int* in_sizes, int n_in,
                              void* d_out, int out_size, void* d_ws, size_t ws_size,
                              hipStream_t stream)
{
  const float* feat = (const float*)d_in[0];
  const int*   src  = (const int*)d_in[1];
  const int*   dst  = (const int*)d_in[2];
  const float* Wq   = (const float*)d_in[3];
  const float* Wk   = (const float*)d_in[4];
  const float* Wv   = (const float*)d_in[5];
  const float* Wo   = (const float*)d_in[6];
  const float* ln1g = (const float*)d_in[7];
  const float* ln1b = (const float*)d_in[8];
  const float* W1   = (const float*)d_in[9];
  const float* b1   = (const float*)d_in[10];
  const float* W2   = (const float*)d_in[11];
  const float* b2   = (const float*)d_in[12];
  const float* ln2g = (const float*)d_in[13];
  const float* ln2b = (const float*)d_in[14];
  float* out = (float*)d_out;

  const int N = in_sizes[0] / DM;
  const int E = in_sizes[1];
  const size_t NB = (size_t)N;

  // workspace layout (bytes):
  // [0)            q_bf  N*256   } mid_bf (N x 512 bf16 = N*1024) aliases q|kv|sav
  // [N*256)        kv_bf N*512
  // [N*768)        sav_bf N*256
  // [N*1024)       h1 f32 N*512
  // [N*1536)       h1b bf16 N*256
  // [N*1792)       feat_bf N*256
  // [N*2048)       weights bf16 (393216 B)
  // then ints: deg N | cur N | off N+1 | csr E | bsum
  char* wsb = (char*)d_ws;
  ushort* q_bf    = (ushort*)wsb;
  ushort* kv_bf   = (ushort*)(wsb + NB * 256);
  ushort* sav_bf  = (ushort*)(wsb + NB * 768);
  ushort* mid_bf  = (ushort*)wsb;
  float*  h1      = (float*)(wsb + NB * 1024);
  ushort* h1b     = (ushort*)(wsb + NB * 1536);
  ushort* feat_bf = (ushort*)(wsb + NB * 1792);
  ushort* wbf     = (ushort*)(wsb + NB * 2048);
  ushort* wqkv_bf = wbf;             // q rows 0-127, k 128-255, v 256-383
  ushort* wo_bf   = wbf + 49152;
  ushort* w1_bf   = wbf + 65536;
  ushort* w2_bf   = wbf + 131072;
  int* ib  = (int*)(wbf + 196608);
  int* deg = ib;
  int* cur = ib + N;
  int* off = ib + 2 * N;
  int* csr = ib + 3 * N + 1;
  int* bsum = csr + E;

  hipMemsetAsync(deg, 0, 2 * (size_t)N * sizeof(int), stream);

  int nf = N * DM;
  k_cast<<<(nf / 4 + 255) / 256, 256, 0, stream>>>(feat, feat_bf, nf);
  k_castw<<<192, 256, 0, stream>>>(Wq, Wk, Wv, Wo, W1, W2, wbf);

  int eb = (E + 255) / 256;
  int nbk = (N + SC_EPB - 1) / SC_EPB;
  k_count<<<eb, 256, 0, stream>>>(dst, deg, E);
  k_scan1<<<nbk, 256, 0, stream>>>(deg, off, bsum, N);
  k_scan2<<<1, 256, 0, stream>>>(bsum, nbk);
  k_scan3<<<nbk, 256, 0, stream>>>(off, bsum, N, E);
  k_scatter<<<eb, 256, 0, stream>>>(src, dst, off, cur, csr, E);

  const int gy = (N + BM - 1) / BM;
  int nb4 = (N + 3) / 4;

  // q = feat @ Wq^T  [N x 128]; kv = feat @ [Wk;Wv]^T  [N x 256]
  k_mm<0, false, true><<<dim3(1, gy), 256, 0, stream>>>(
      feat_bf, wqkv_bf, nullptr, nullptr, nullptr, nullptr, nullptr, q_bf, N, DM, DM);
  k_mm<0, false, true><<<dim3(2, gy), 256, 0, stream>>>(
      feat_bf, wqkv_bf + 16384, nullptr, nullptr, nullptr, nullptr, nullptr, kv_bf, N, 256, DM);

  k_attn<<<nb4, 256, 0, stream>>>(q_bf, kv_bf, off, csr, sav_bf, N);

  // h1 = LN1(sav @ Wo^T + feat)  -> h1 (f32) + h1b (bf16), fused epilogue
  k_mm<4 | 8, true, true><<<dim3(1, gy), 256, 0, stream>>>(
      sav_bf, wo_bf, nullptr, feat, ln1g, ln1b, h1, h1b, N, DM, DM);

  // mid = relu(h1 @ W1^T + b1)  [N x 512] bf16
  k_mm<1 | 2, false, true><<<dim3(4, gy), 256, 0, stream>>>(
      h1b, w1_bf, b1, nullptr, nullptr, nullptr, nullptr, mid_bf, N, DFF, DM);

  // out = LN2(mid @ W2^T + b2 + h1), fused epilogue
  k_mm<1 | 4 | 8, true, false><<<dim3(1, gy), 256, 0, stream>>>(
      mid_bf, w2_bf, b2, h1, ln2g, ln2b, out, nullptr, N, DM, DFF);
}

// Round 6
// 203.525 us; speedup vs baseline: 1.2060x; 1.2060x over previous
//
#include <hip/hip_runtime.h>

#define DM 128
#define DFF 512
#define CLAMP_V 5.0f
#define LN_EPS 1e-5f

typedef __attribute__((ext_vector_type(8))) short bf16x8;
typedef __attribute__((ext_vector_type(4))) float f32x4;

__device__ __forceinline__ float b2f(ushort u) {
  union { uint u; float f; } x; x.u = ((uint)u) << 16; return x.f;
}
__device__ __forceinline__ ushort f2b(float f) {
  union { float f; uint u; } x; x.f = f;
  uint r = x.u + 0x7FFFu + ((x.u >> 16) & 1u);
  return (ushort)(r >> 16);
}
__device__ __forceinline__ void unpackw(uint w, float& lo, float& hi) {
  union { uint u; float f; } A, B;
  A.u = w << 16; B.u = w & 0xFFFF0000u;
  lo = A.f; hi = B.f;
}
__device__ __forceinline__ void unpack8w(uint4 w, float* o) {
  unpackw(w.x, o[0], o[1]); unpackw(w.y, o[2], o[3]);
  unpackw(w.z, o[4], o[5]); unpackw(w.w, o[6], o[7]);
}

// ---------------- casts ----------------
__global__ void k_cast(const float* __restrict__ s, ushort* __restrict__ d, int n) {
  int i4 = (blockIdx.x * blockDim.x + threadIdx.x) * 4;
  if (i4 + 3 < n) {
    float4 v = *reinterpret_cast<const float4*>(s + i4);
    ushort4 o; o.x = f2b(v.x); o.y = f2b(v.y); o.z = f2b(v.z); o.w = f2b(v.w);
    *reinterpret_cast<ushort4*>(d + i4) = o;
  } else {
    for (; i4 < n; ++i4) d[i4] = f2b(s[i4]);
  }
}

__global__ void k_castw(const float* __restrict__ wq, const float* __restrict__ wk,
                        const float* __restrict__ wv, const float* __restrict__ wo,
                        const float* __restrict__ w1, const float* __restrict__ w2,
                        ushort* __restrict__ d) {
  int i4 = (blockIdx.x * blockDim.x + threadIdx.x) * 4;
  if (i4 >= 196608) return;
  const float* s; int o;
  if      (i4 < 16384)  { s = wq; o = i4; }
  else if (i4 < 32768)  { s = wk; o = i4 - 16384; }
  else if (i4 < 49152)  { s = wv; o = i4 - 32768; }
  else if (i4 < 65536)  { s = wo; o = i4 - 49152; }
  else if (i4 < 131072) { s = w1; o = i4 - 65536; }
  else                  { s = w2; o = i4 - 131072; }
  float4 v = *reinterpret_cast<const float4*>(s + o);
  ushort4 u; u.x = f2b(v.x); u.y = f2b(v.y); u.z = f2b(v.z); u.w = f2b(v.w);
  *reinterpret_cast<ushort4*>(d + i4) = u;
}

// ---------------- CSR build ----------------
__global__ void k_count(const int* __restrict__ dst, int* __restrict__ deg, int E) {
  int e = blockIdx.x * blockDim.x + threadIdx.x;
  if (e < E) atomicAdd(&deg[dst[e]], 1);
}

#define SC_EPB 1024

__global__ __launch_bounds__(256) void k_scan1(const int* __restrict__ deg,
                                               int* __restrict__ off,
                                               int* __restrict__ bsum, int n) {
  __shared__ int sh[256];
  const int t = threadIdx.x;
  int base = blockIdx.x * SC_EPB + t * 4;
  int4 v = {0, 0, 0, 0};
  if (base + 3 < n) {
    v = *reinterpret_cast<const int4*>(deg + base);
  } else {
    if (base     < n) v.x = deg[base];
    if (base + 1 < n) v.y = deg[base + 1];
    if (base + 2 < n) v.z = deg[base + 2];
    if (base + 3 < n) v.w = deg[base + 3];
  }
  int s = v.x + v.y + v.z + v.w;
  sh[t] = s;
  __syncthreads();
  #pragma unroll
  for (int d = 1; d < 256; d <<= 1) {
    int x = 0;
    if (t >= d) x = sh[t - d];
    __syncthreads();
    sh[t] += x;
    __syncthreads();
  }
  int ex = sh[t] - s;
  if (base + 3 < n) {
    int4 o; o.x = ex; o.y = ex + v.x; o.z = ex + v.x + v.y; o.w = ex + v.x + v.y + v.z;
    *reinterpret_cast<int4*>(off + base) = o;
  } else {
    if (base     < n) off[base]     = ex;
    if (base + 1 < n) off[base + 1] = ex + v.x;
    if (base + 2 < n) off[base + 2] = ex + v.x + v.y;
    if (base + 3 < n) off[base + 3] = ex + v.x + v.y + v.z;
  }
  if (t == 255) bsum[blockIdx.x] = sh[255];
}

__global__ __launch_bounds__(256) void k_scan2(int* __restrict__ bsum, int nb) {
  __shared__ int sh[256];
  const int t = threadIdx.x;
  int v = (t < nb) ? bsum[t] : 0;
  sh[t] = v;
  __syncthreads();
  #pragma unroll
  for (int d = 1; d < 256; d <<= 1) {
    int x = 0;
    if (t >= d) x = sh[t - d];
    __syncthreads();
    sh[t] += x;
    __syncthreads();
  }
  if (t < nb) bsum[t] = sh[t] - v;
}

__global__ __launch_bounds__(256) void k_scan3(int* __restrict__ off,
                                               const int* __restrict__ bsum,
                                               int n, int E) {
  int add = bsum[blockIdx.x];
  int base = blockIdx.x * SC_EPB + threadIdx.x * 4;
  if (base + 3 < n) {
    int4 v = *reinterpret_cast<int4*>(off + base);
    v.x += add; v.y += add; v.z += add; v.w += add;
    *reinterpret_cast<int4*>(off + base) = v;
  } else {
    if (base     < n) off[base]     += add;
    if (base + 1 < n) off[base + 1] += add;
    if (base + 2 < n) off[base + 2] += add;
  }
  if (blockIdx.x == 0 && threadIdx.x == 0) off[n] = E;
}

__global__ void k_scatter(const int* __restrict__ src, const int* __restrict__ dst,
                          const int* __restrict__ off, int* __restrict__ cur,
                          int* __restrict__ csr, int E) {
  int e = blockIdx.x * blockDim.x + threadIdx.x;
  if (e < E) {
    int d = dst[e];
    int p = off[d] + atomicAdd(&cur[d], 1);
    csr[p] = src[e];
  }
}

// ---------------- bf16 MFMA GEMM, optional fused register-space LayerNorm ----------
// FLAGS: 1=bias 2=relu 4=residual 8=fused-LN (requires NO==BN==128, bn==0)
#define BM 128
#define BN 128
#define BK 64

template<int FLAGS, bool OUTF, bool OUTB>
__global__ __launch_bounds__(256, 3) void k_mm(
    const ushort* __restrict__ A, const ushort* __restrict__ W,
    const float* __restrict__ bias, const float* __restrict__ res,
    const float* __restrict__ lng, const float* __restrict__ lnbv,
    float* __restrict__ Cf, ushort* __restrict__ Cb,
    int M, int NO, int K)
{
  __shared__ ushort As[BM * BK];
  __shared__ ushort Ws[BN * BK];
  __shared__ float lnred[(FLAGS & 8) ? 512 : 4];   // [row][sum0,sq0,sum1,sq1]

  const int tid = threadIdx.x;
  const int wv = tid >> 6, ln = tid & 63;
  const int bm = blockIdx.y * BM, bn = blockIdx.x * BN;
  const int wrow = (wv >> 1) * 64, wcol = (wv & 1) * 64;

  f32x4 acc[4][4] = {};
  const int o_base = wv * 1024 + ln * 16;

  for (int k0 = 0; k0 < K; k0 += BK) {
    #pragma unroll
    for (int is = 0; is < 4; ++is) {
      int o = is * 4096 + o_base;
      int row = o >> 7;
      int c = ((o >> 4) & 7) ^ (row & 7);
      int gm = bm + row; if (gm >= M) gm = M - 1;
      const ushort* srcA = A + (size_t)gm * K + k0 + c * 8;
      __builtin_amdgcn_global_load_lds(
          (const __attribute__((address_space(1))) void*)srcA,
          (__attribute__((address_space(3))) void*)((char*)As + is * 4096 + wv * 1024),
          16, 0, 0);
      int gn = bn + row;
      const ushort* srcW = W + (size_t)gn * K + k0 + c * 8;
      __builtin_amdgcn_global_load_lds(
          (const __attribute__((address_space(1))) void*)srcW,
          (__attribute__((address_space(3))) void*)((char*)Ws + is * 4096 + wv * 1024),
          16, 0, 0);
    }
    __syncthreads();

    const char* AsB = (const char*)As;
    const char* WsB = (const char*)Ws;
    #pragma unroll
    for (int kk = 0; kk < 2; ++kk) {
      bf16x8 af[4], bf[4];
      #pragma unroll
      for (int m = 0; m < 4; ++m) {
        int r = wrow + m * 16 + (ln & 15);
        int c = kk * 4 + (ln >> 4);
        af[m] = *reinterpret_cast<const bf16x8*>(AsB + r * 128 + ((c ^ (r & 7)) << 4));
      }
      #pragma unroll
      for (int n = 0; n < 4; ++n) {
        int r = wcol + n * 16 + (ln & 15);
        int c = kk * 4 + (ln >> 4);
        bf[n] = *reinterpret_cast<const bf16x8*>(WsB + r * 128 + ((c ^ (r & 7)) << 4));
      }
      #pragma unroll
      for (int m = 0; m < 4; ++m)
        #pragma unroll
        for (int n = 0; n < 4; ++n)
          acc[m][n] = __builtin_amdgcn_mfma_f32_16x16x32_bf16(af[m], bf[n], acc[m][n], 0, 0, 0);
    }
    __syncthreads();
  }

  if constexpr ((FLAGS & 8) != 0) {
    // ---- register-space LN epilogue (NO == 128, bn == 0) ----
    // 1) finish elementwise ops in-place
    #pragma unroll
    for (int m = 0; m < 4; ++m)
      #pragma unroll
      for (int n = 0; n < 4; ++n) {
        int gc = wcol + n * 16 + (ln & 15);
        float bsv = (FLAGS & 1) ? bias[gc] : 0.f;
        #pragma unroll
        for (int r = 0; r < 4; ++r) {
          int gr = bm + wrow + m * 16 + (ln >> 4) * 4 + r;
          float v = acc[m][n][r] + bsv;
          if (FLAGS & 2) v = fmaxf(v, 0.f);
          if (FLAGS & 4) v += res[(size_t)min(gr, M - 1) * 128 + gc];
          acc[m][n][r] = v;
        }
      }
    // 2) per-row partial sum/sumsq over this wave's 64-col half
    #pragma unroll
    for (int m = 0; m < 4; ++m)
      #pragma unroll
      for (int r = 0; r < 4; ++r) {
        float sm = acc[m][0][r] + acc[m][1][r] + acc[m][2][r] + acc[m][3][r];
        float sq = acc[m][0][r] * acc[m][0][r] + acc[m][1][r] * acc[m][1][r]
                 + acc[m][2][r] * acc[m][2][r] + acc[m][3][r] * acc[m][3][r];
        #pragma unroll
        for (int msk = 1; msk <= 8; msk <<= 1) {
          sm += __shfl_xor(sm, msk);
          sq += __shfl_xor(sq, msk);
        }
        if ((ln & 15) == 0) {
          int row = wrow + m * 16 + (ln >> 4) * 4 + r;
          lnred[row * 4 + (wv & 1) * 2]     = sm;
          lnred[row * 4 + (wv & 1) * 2 + 1] = sq;
        }
      }
    __syncthreads();
    // 3) normalize own fragments and store
    #pragma unroll
    for (int m = 0; m < 4; ++m)
      #pragma unroll
      for (int r = 0; r < 4; ++r) {
        int row = wrow + m * 16 + (ln >> 4) * 4 + r;
        int gr = bm + row;
        float sm = lnred[row * 4] + lnred[row * 4 + 2];
        float sq = lnred[row * 4 + 1] + lnred[row * 4 + 3];
        float mu = sm * (1.f / 128.f);
        float var = fmaxf(sq * (1.f / 128.f) - mu * mu, 0.f);
        float rstd = rsqrtf(var + LN_EPS);
        if (gr < M) {
          #pragma unroll
          for (int n = 0; n < 4; ++n) {
            int gc = wcol + n * 16 + (ln & 15);
            float y = (acc[m][n][r] - mu) * rstd * lng[gc] + lnbv[gc];
            if (OUTF) Cf[(size_t)gr * 128 + gc] = y;
            if (OUTB) Cb[(size_t)gr * 128 + gc] = f2b(y);
          }
        }
      }
  } else {
    #pragma unroll
    for (int m = 0; m < 4; ++m) {
      int gr0 = bm + wrow + m * 16 + (ln >> 4) * 4;
      #pragma unroll
      for (int n = 0; n < 4; ++n) {
        int gc = bn + wcol + n * 16 + (ln & 15);
        float bsv = (FLAGS & 1) ? bias[gc] : 0.f;
        #pragma unroll
        for (int r = 0; r < 4; ++r) {
          int gr = gr0 + r;
          if (gr >= M) continue;
          float v = acc[m][n][r] + bsv;
          if (FLAGS & 2) v = fmaxf(v, 0.f);
          if (FLAGS & 4) v += res[(size_t)gr * NO + gc];
          if (OUTF) Cf[(size_t)gr * NO + gc] = v;
          if (OUTB) Cb[(size_t)gr * NO + gc] = f2b(v);
        }
      }
    }
  }
}

// ---------------- edge-softmax attention: 8 groups x 8 lanes, lane = full head ----
__global__ __launch_bounds__(256) void k_attn(
    const ushort* __restrict__ q, const ushort* __restrict__ kv,
    const int* __restrict__ off, const int* __restrict__ csr,
    ushort* __restrict__ sav, int n)
{
  int node = blockIdx.x * 4 + (threadIdx.x >> 6);
  int lane = threadIdx.x & 63;
  if (node >= n) return;
  const int g = lane >> 3, sl = lane & 7;

  const ushort* qr = q + (size_t)node * 128 + sl * 16;
  uint4 qw0 = *reinterpret_cast<const uint4*>(qr);
  uint4 qw1 = *reinterpret_cast<const uint4*>(qr + 8);
  float qv[16];
  unpack8w(qw0, qv); unpack8w(qw1, qv + 8);

  int b = off[node], e = off[node + 1];
  float m = -1e30f, s = 0.f;
  float a[16] = {};
  int nIt = (e - b + 7) >> 3;
  int idx = b + g;
  int sn = (b < e) ? csr[min(idx, e - 1)] : 0;

  for (int i = 0; i < nIt; ++i) {
    bool act = idx < e;
    const ushort* kr = kv + (size_t)sn * 256 + sl * 16;
    uint4 kw0 = *reinterpret_cast<const uint4*>(kr);
    uint4 kw1 = *reinterpret_cast<const uint4*>(kr + 8);
    uint4 vw0 = *reinterpret_cast<const uint4*>(kr + 128);
    uint4 vw1 = *reinterpret_cast<const uint4*>(kr + 136);
    idx += 8;
    if (i + 1 < nIt) sn = csr[min(idx, e - 1)];

    float kk[16];
    unpack8w(kw0, kk); unpack8w(kw1, kk + 8);
    float p = 0.f;
    #pragma unroll
    for (int j = 0; j < 16; ++j) p = fmaf(qv[j], kk[j], p);
    float u = fminf(fmaxf(p * 0.25f, -CLAMP_V), CLAMP_V);
    if (act) {
      float mn = fmaxf(m, u);
      float f = __expf(m - mn);
      float w = __expf(u - mn);
      s = s * f + w;
      float vvv[16];
      unpack8w(vw0, vvv); unpack8w(vw1, vvv + 8);
      #pragma unroll
      for (int j = 0; j < 16; ++j) a[j] = a[j] * f + w * vvv[j];
      m = mn;
    }
  }

  #pragma unroll
  for (int msk = 8; msk <= 32; msk <<= 1) {
    float mo = __shfl_xor(m, msk);
    float so = __shfl_xor(s, msk);
    float ao[16];
    #pragma unroll
    for (int j = 0; j < 16; ++j) ao[j] = __shfl_xor(a[j], msk);
    float mn = fmaxf(m, mo);
    float f1 = __expf(m - mn), f2 = __expf(mo - mn);
    s = s * f1 + so * f2;
    #pragma unroll
    for (int j = 0; j < 16; ++j) a[j] = a[j] * f1 + ao[j] * f2;
    m = mn;
  }

  float inv = (s > 0.f) ? 1.f / s : 0.f;
  if (g == 0) {
    uint w[8];
    #pragma unroll
    for (int j = 0; j < 8; ++j)
      w[j] = (uint)f2b(a[2 * j] * inv) | ((uint)f2b(a[2 * j + 1] * inv) << 16);
    ushort* outp = sav + (size_t)node * 128 + sl * 16;
    uint4 o0 = {w[0], w[1], w[2], w[3]};
    uint4 o1 = {w[4], w[5], w[6], w[7]};
    *reinterpret_cast<uint4*>(outp) = o0;
    *reinterpret_cast<uint4*>(outp + 8) = o1;
  }
}

extern "C" void kernel_launch(void* const* d_in, const int* in_sizes, int n_in,
                              void* d_out, int out_size, void* d_ws, size_t ws_size,
                              hipStream_t stream)
{
  const float* feat = (const float*)d_in[0];
  const int*   src  = (const int*)d_in[1];
  const int*   dst  = (const int*)d_in[2];
  const float* Wq   = (const float*)d_in[3];
  const float* Wk   = (const float*)d_in[4];
  const float* Wv   = (const float*)d_in[5];
  const float* Wo   = (const float*)d_in[6];
  const float* ln1g = (const float*)d_in[7];
  const float* ln1b = (const float*)d_in[8];
  const float* W1   = (const float*)d_in[9];
  const float* b1   = (const float*)d_in[10];
  const float* W2   = (const float*)d_in[11];
  const float* b2   = (const float*)d_in[12];
  const float* ln2g = (const float*)d_in[13];
  const float* ln2b = (const float*)d_in[14];
  float* out = (float*)d_out;

  const int N = in_sizes[0] / DM;
  const int E = in_sizes[1];
  const size_t NB = (size_t)N;

  char* wsb = (char*)d_ws;
  ushort* q_bf    = (ushort*)wsb;
  ushort* kv_bf   = (ushort*)(wsb + NB * 256);
  ushort* sav_bf  = (ushort*)(wsb + NB * 768);
  ushort* mid_bf  = (ushort*)wsb;
  float*  h1      = (float*)(wsb + NB * 1024);
  ushort* h1b     = (ushort*)(wsb + NB * 1536);
  ushort* feat_bf = (ushort*)(wsb + NB * 1792);
  ushort* wbf     = (ushort*)(wsb + NB * 2048);
  ushort* wqkv_bf = wbf;
  ushort* wo_bf   = wbf + 49152;
  ushort* w1_bf   = wbf + 65536;
  ushort* w2_bf   = wbf + 131072;
  int* ib  = (int*)(wbf + 196608);
  int* deg = ib;
  int* cur = ib + N;
  int* off = ib + 2 * N;
  int* csr = ib + 3 * N + 1;
  int* bsum = csr + E;

  hipMemsetAsync(deg, 0, 2 * (size_t)N * sizeof(int), stream);

  int nf = N * DM;
  k_cast<<<(nf / 4 + 255) / 256, 256, 0, stream>>>(feat, feat_bf, nf);
  k_castw<<<192, 256, 0, stream>>>(Wq, Wk, Wv, Wo, W1, W2, wbf);

  int eb = (E + 255) / 256;
  int nbk = (N + SC_EPB - 1) / SC_EPB;
  k_count<<<eb, 256, 0, stream>>>(dst, deg, E);
  k_scan1<<<nbk, 256, 0, stream>>>(deg, off, bsum, N);
  k_scan2<<<1, 256, 0, stream>>>(bsum, nbk);
  k_scan3<<<nbk, 256, 0, stream>>>(off, bsum, N, E);
  k_scatter<<<eb, 256, 0, stream>>>(src, dst, off, cur, csr, E);

  const int gy = (N + BM - 1) / BM;
  int nb4 = (N + 3) / 4;

  k_mm<0, false, true><<<dim3(1, gy), 256, 0, stream>>>(
      feat_bf, wqkv_bf, nullptr, nullptr, nullptr, nullptr, nullptr, q_bf, N, DM, DM);
  k_mm<0, false, true><<<dim3(2, gy), 256, 0, stream>>>(
      feat_bf, wqkv_bf + 16384, nullptr, nullptr, nullptr, nullptr, nullptr, kv_bf, N, 256, DM);

  k_attn<<<nb4, 256, 0, stream>>>(q_bf, kv_bf, off, csr, sav_bf, N);

  // h1 = LN1(sav @ Wo^T + feat)  -> h1 (f32) + h1b (bf16)
  k_mm<4 | 8, true, true><<<dim3(1, gy), 256, 0, stream>>>(
      sav_bf, wo_bf, nullptr, feat, ln1g, ln1b, h1, h1b, N, DM, DM);

  // mid = relu(h1 @ W1^T + b1)
  k_mm<1 | 2, false, true><<<dim3(4, gy), 256, 0, stream>>>(
      h1b, w1_bf, b1, nullptr, nullptr, nullptr, nullptr, mid_bf, N, DFF, DM);

  // out = LN2(mid @ W2^T + b2 + h1)
  k_mm<1 | 4 | 8, true, false><<<dim3(1, gy), 256, 0, stream>>>(
      mid_bf, w2_bf, b2, h1, ln2g, ln2b, out, nullptr, N, DM, DFF);
}

// Round 7
// 199.945 us; speedup vs baseline: 1.2276x; 1.0179x over previous
//
#include <hip/hip_runtime.h>

#define DM 128
#define DFF 512
#define CLAMP_V 5.0f
#define LN_EPS 1e-5f

typedef __attribute__((ext_vector_type(8))) short bf16x8;
typedef __attribute__((ext_vector_type(4))) float f32x4;

__device__ __forceinline__ float b2f(ushort u) {
  union { uint u; float f; } x; x.u = ((uint)u) << 16; return x.f;
}
__device__ __forceinline__ ushort f2b(float f) {
  union { float f; uint u; } x; x.f = f;
  uint r = x.u + 0x7FFFu + ((x.u >> 16) & 1u);
  return (ushort)(r >> 16);
}
__device__ __forceinline__ void unpackw(uint w, float& lo, float& hi) {
  union { uint u; float f; } A, B;
  A.u = w << 16; B.u = w & 0xFFFF0000u;
  lo = A.f; hi = B.f;
}
__device__ __forceinline__ void unpack8w(uint4 w, float* o) {
  unpackw(w.x, o[0], o[1]); unpackw(w.y, o[2], o[3]);
  unpackw(w.z, o[4], o[5]); unpackw(w.w, o[6], o[7]);
}

// ---------------- casts ----------------
__global__ void k_cast(const float* __restrict__ s, ushort* __restrict__ d, int n) {
  int i4 = (blockIdx.x * blockDim.x + threadIdx.x) * 4;
  if (i4 + 3 < n) {
    float4 v = *reinterpret_cast<const float4*>(s + i4);
    ushort4 o; o.x = f2b(v.x); o.y = f2b(v.y); o.z = f2b(v.z); o.w = f2b(v.w);
    *reinterpret_cast<ushort4*>(d + i4) = o;
  } else {
    for (; i4 < n; ++i4) d[i4] = f2b(s[i4]);
  }
}

__global__ void k_castw(const float* __restrict__ wq, const float* __restrict__ wk,
                        const float* __restrict__ wv, const float* __restrict__ wo,
                        const float* __restrict__ w1, const float* __restrict__ w2,
                        ushort* __restrict__ d) {
  int i4 = (blockIdx.x * blockDim.x + threadIdx.x) * 4;
  if (i4 >= 196608) return;
  const float* s; int o;
  if      (i4 < 16384)  { s = wq; o = i4; }
  else if (i4 < 32768)  { s = wk; o = i4 - 16384; }
  else if (i4 < 49152)  { s = wv; o = i4 - 32768; }
  else if (i4 < 65536)  { s = wo; o = i4 - 49152; }
  else if (i4 < 131072) { s = w1; o = i4 - 65536; }
  else                  { s = w2; o = i4 - 131072; }
  float4 v = *reinterpret_cast<const float4*>(s + o);
  ushort4 u; u.x = f2b(v.x); u.y = f2b(v.y); u.z = f2b(v.z); u.w = f2b(v.w);
  *reinterpret_cast<ushort4*>(d + i4) = u;
}

// ---------------- CSR build ----------------
__global__ void k_count(const int* __restrict__ dst, int* __restrict__ deg, int E) {
  int e = blockIdx.x * blockDim.x + threadIdx.x;
  if (e < E) atomicAdd(&deg[dst[e]], 1);
}

#define SC_EPB 1024

__global__ __launch_bounds__(256) void k_scan1(const int* __restrict__ deg,
                                               int* __restrict__ off,
                                               int* __restrict__ bsum, int n) {
  __shared__ int sh[256];
  const int t = threadIdx.x;
  int base = blockIdx.x * SC_EPB + t * 4;
  int4 v = {0, 0, 0, 0};
  if (base + 3 < n) {
    v = *reinterpret_cast<const int4*>(deg + base);
  } else {
    if (base     < n) v.x = deg[base];
    if (base + 1 < n) v.y = deg[base + 1];
    if (base + 2 < n) v.z = deg[base + 2];
    if (base + 3 < n) v.w = deg[base + 3];
  }
  int s = v.x + v.y + v.z + v.w;
  sh[t] = s;
  __syncthreads();
  #pragma unroll
  for (int d = 1; d < 256; d <<= 1) {
    int x = 0;
    if (t >= d) x = sh[t - d];
    __syncthreads();
    sh[t] += x;
    __syncthreads();
  }
  int ex = sh[t] - s;
  if (base + 3 < n) {
    int4 o; o.x = ex; o.y = ex + v.x; o.z = ex + v.x + v.y; o.w = ex + v.x + v.y + v.z;
    *reinterpret_cast<int4*>(off + base) = o;
  } else {
    if (base     < n) off[base]     = ex;
    if (base + 1 < n) off[base + 1] = ex + v.x;
    if (base + 2 < n) off[base + 2] = ex + v.x + v.y;
    if (base + 3 < n) off[base + 3] = ex + v.x + v.y + v.z;
  }
  if (t == 255) bsum[blockIdx.x] = sh[255];
}

__global__ __launch_bounds__(256) void k_scan2(int* __restrict__ bsum, int nb) {
  __shared__ int sh[256];
  const int t = threadIdx.x;
  int v = (t < nb) ? bsum[t] : 0;
  sh[t] = v;
  __syncthreads();
  #pragma unroll
  for (int d = 1; d < 256; d <<= 1) {
    int x = 0;
    if (t >= d) x = sh[t - d];
    __syncthreads();
    sh[t] += x;
    __syncthreads();
  }
  if (t < nb) bsum[t] = sh[t] - v;
}

__global__ __launch_bounds__(256) void k_scan3(int* __restrict__ off,
                                               const int* __restrict__ bsum,
                                               int n, int E) {
  int add = bsum[blockIdx.x];
  int base = blockIdx.x * SC_EPB + threadIdx.x * 4;
  if (base + 3 < n) {
    int4 v = *reinterpret_cast<int4*>(off + base);
    v.x += add; v.y += add; v.z += add; v.w += add;
    *reinterpret_cast<int4*>(off + base) = v;
  } else {
    if (base     < n) off[base]     += add;
    if (base + 1 < n) off[base + 1] += add;
    if (base + 2 < n) off[base + 2] += add;
  }
  if (blockIdx.x == 0 && threadIdx.x == 0) off[n] = E;
}

__global__ void k_scatter(const int* __restrict__ src, const int* __restrict__ dst,
                          const int* __restrict__ off, int* __restrict__ cur,
                          int* __restrict__ csr, int E) {
  int e = blockIdx.x * blockDim.x + threadIdx.x;
  if (e < E) {
    int d = dst[e];
    int p = off[d] + atomicAdd(&cur[d], 1);
    csr[p] = src[e];
  }
}

// =====================================================================
// k_mmS: weight-stationary GEMM for K=128. B panel (128 out-cols x 128) in
// LDS once per block; loop over M-tiles with double-buffered A and the
// 2-phase order (issue stage(t+1) BEFORE compute(t), one barrier per tile).
// 512 threads = 8 waves (2 rows x 4 cols of 64x32 wave-tiles).
// FLAGS: 1=bias 2=relu 4=residual(f32,128w) 8=LN (needs gridDim.x==1)
// =====================================================================
template<int FLAGS, bool QKVSPLIT, bool OUTF, bool OUTB>
__global__ __launch_bounds__(512, 1) void k_mmS(
    const ushort* __restrict__ A, const ushort* __restrict__ W,
    const float* __restrict__ bias, const float* __restrict__ res,
    const float* __restrict__ lng, const float* __restrict__ lnbv,
    float* __restrict__ Cf, ushort* __restrict__ Cb, ushort* __restrict__ Cb2,
    int M, int ldc)
{
  __shared__ ushort Bs[128 * 128];
  __shared__ ushort As[2][128 * 128];
  __shared__ float lnred[(FLAGS & 8) ? 1024 : 4];

  const int tid = threadIdx.x;
  const int wv = tid >> 6, ln = tid & 63;
  const int bnb = blockIdx.x;
  const int wrow = (wv >> 2) * 64, wcol = (wv & 3) * 32;
  const int o_base = wv * 1024 + ln * 16;

  const int nT = (M + 127) >> 7;
  const int T = (nT + gridDim.y - 1) / gridDim.y;
  const int t0 = blockIdx.y * T;
  const int t1 = min(t0 + T, nT);
  if (t0 >= nT) return;

  // ---- stage B panel (once) ----
  #pragma unroll
  for (int is = 0; is < 4; ++is) {
    int o = is * 8192 + o_base;
    int row = o >> 8;
    int c = ((o >> 4) & 15) ^ (row & 15);
    const ushort* s = W + (size_t)(bnb * 128 + row) * 128 + c * 8;
    __builtin_amdgcn_global_load_lds(
        (const __attribute__((address_space(1))) void*)s,
        (__attribute__((address_space(3))) void*)((char*)Bs + is * 8192 + wv * 1024),
        16, 0, 0);
  }
  // ---- stage A tile t0 into buf 0 ----
  {
    #pragma unroll
    for (int is = 0; is < 4; ++is) {
      int o = is * 8192 + o_base;
      int row = o >> 8;
      int c = ((o >> 4) & 15) ^ (row & 15);
      int gr = min(t0 * 128 + row, M - 1);
      const ushort* s = A + (size_t)gr * 128 + c * 8;
      __builtin_amdgcn_global_load_lds(
          (const __attribute__((address_space(1))) void*)s,
          (__attribute__((address_space(3))) void*)((char*)As[0] + is * 8192 + wv * 1024),
          16, 0, 0);
    }
  }
  __syncthreads();

  int buf = 0;
  for (int t = t0; t < t1; ++t) {
    // issue next tile's stage first (overlaps with compute below)
    if (t + 1 < t1) {
      #pragma unroll
      for (int is = 0; is < 4; ++is) {
        int o = is * 8192 + o_base;
        int row = o >> 8;
        int c = ((o >> 4) & 15) ^ (row & 15);
        int gr = min((t + 1) * 128 + row, M - 1);
        const ushort* s = A + (size_t)gr * 128 + c * 8;
        __builtin_amdgcn_global_load_lds(
            (const __attribute__((address_space(1))) void*)s,
            (__attribute__((address_space(3))) void*)((char*)As[buf ^ 1] + is * 8192 + wv * 1024),
            16, 0, 0);
      }
    }

    // ---- compute tile t from As[buf], Bs ----
    f32x4 acc[4][2] = {};
    const char* AsB = (const char*)As[buf];
    const char* BsB = (const char*)Bs;
    #pragma unroll
    for (int kk = 0; kk < 4; ++kk) {
      bf16x8 af[4], bfr[2];
      #pragma unroll
      for (int m = 0; m < 4; ++m) {
        int r = wrow + m * 16 + (ln & 15);
        int c = kk * 4 + (ln >> 4);
        af[m] = *reinterpret_cast<const bf16x8*>(AsB + r * 256 + ((c ^ (r & 15)) << 4));
      }
      #pragma unroll
      for (int n = 0; n < 2; ++n) {
        int r = wcol + n * 16 + (ln & 15);
        int c = kk * 4 + (ln >> 4);
        bfr[n] = *reinterpret_cast<const bf16x8*>(BsB + r * 256 + ((c ^ (r & 15)) << 4));
      }
      #pragma unroll
      for (int m = 0; m < 4; ++m)
        #pragma unroll
        for (int n = 0; n < 2; ++n)
          acc[m][n] = __builtin_amdgcn_mfma_f32_16x16x32_bf16(af[m], bfr[n], acc[m][n], 0, 0, 0);
    }

    const int mbase = t * 128;
    if constexpr ((FLAGS & 8) != 0) {
      // ---- fused LN epilogue (gridDim.x==1, 128 cols) ----
      #pragma unroll
      for (int m = 0; m < 4; ++m)
        #pragma unroll
        for (int n = 0; n < 2; ++n) {
          int gc = wcol + n * 16 + (ln & 15);
          #pragma unroll
          for (int r = 0; r < 4; ++r) {
            int gr = mbase + wrow + m * 16 + (ln >> 4) * 4 + r;
            float v = acc[m][n][r];
            if (FLAGS & 1) v += bias[gc];
            if (FLAGS & 2) v = fmaxf(v, 0.f);
            if (FLAGS & 4) v += res[(size_t)min(gr, M - 1) * 128 + gc];
            acc[m][n][r] = v;
          }
        }
      #pragma unroll
      for (int m = 0; m < 4; ++m)
        #pragma unroll
        for (int r = 0; r < 4; ++r) {
          float sm = acc[m][0][r] + acc[m][1][r];
          float sq = acc[m][0][r] * acc[m][0][r] + acc[m][1][r] * acc[m][1][r];
          #pragma unroll
          for (int msk = 1; msk <= 8; msk <<= 1) {
            sm += __shfl_xor(sm, msk);
            sq += __shfl_xor(sq, msk);
          }
          if ((ln & 15) == 0) {
            int row = wrow + m * 16 + (ln >> 4) * 4 + r;
            lnred[row * 8 + (wv & 3) * 2]     = sm;
            lnred[row * 8 + (wv & 3) * 2 + 1] = sq;
          }
        }
      __syncthreads();
      #pragma unroll
      for (int m = 0; m < 4; ++m)
        #pragma unroll
        for (int r = 0; r < 4; ++r) {
          int row = wrow + m * 16 + (ln >> 4) * 4 + r;
          int gr = mbase + row;
          float sm = lnred[row * 8] + lnred[row * 8 + 2] + lnred[row * 8 + 4] + lnred[row * 8 + 6];
          float sq = lnred[row * 8 + 1] + lnred[row * 8 + 3] + lnred[row * 8 + 5] + lnred[row * 8 + 7];
          float mu = sm * (1.f / 128.f);
          float var = fmaxf(sq * (1.f / 128.f) - mu * mu, 0.f);
          float rstd = rsqrtf(var + LN_EPS);
          if (gr < M) {
            #pragma unroll
            for (int n = 0; n < 2; ++n) {
              int gc = wcol + n * 16 + (ln & 15);
              float y = (acc[m][n][r] - mu) * rstd * lng[gc] + lnbv[gc];
              if (OUTF) Cf[(size_t)gr * 128 + gc] = y;
              if (OUTB) Cb[(size_t)gr * 128 + gc] = f2b(y);
            }
          }
        }
    } else {
      #pragma unroll
      for (int m = 0; m < 4; ++m) {
        int gr0 = mbase + wrow + m * 16 + (ln >> 4) * 4;
        #pragma unroll
        for (int n = 0; n < 2; ++n) {
          int gcl = wcol + n * 16 + (ln & 15);
          float bsv = (FLAGS & 1) ? bias[bnb * 128 + gcl] : 0.f;
          #pragma unroll
          for (int r = 0; r < 4; ++r) {
            int gr = gr0 + r;
            if (gr >= M) continue;
            float v = acc[m][n][r] + bsv;
            if (FLAGS & 2) v = fmaxf(v, 0.f);
            if (QKVSPLIT) {
              if (bnb == 0) Cb[(size_t)gr * 128 + gcl] = f2b(v);
              else          Cb2[(size_t)gr * 256 + (bnb - 1) * 128 + gcl] = f2b(v);
            } else {
              if (OUTF) Cf[(size_t)gr * ldc + bnb * 128 + gcl] = v;
              if (OUTB) Cb[(size_t)gr * ldc + bnb * 128 + gcl] = f2b(v);
            }
          }
        }
      }
    }
    __syncthreads();
    buf ^= 1;
  }
}

// =====================================================================
// k_mm2: K-looped GEMM (for K=512 ffn2) with double-buffered LDS and
// 2-phase order. 256 threads, 4 waves (2x2 of 64x64). LN epilogue option.
// =====================================================================
#define BM 128
#define BN 128
#define BK 64

template<int FLAGS, bool OUTF, bool OUTB>
__global__ __launch_bounds__(256, 2) void k_mm2(
    const ushort* __restrict__ A, const ushort* __restrict__ W,
    const float* __restrict__ bias, const float* __restrict__ res,
    const float* __restrict__ lng, const float* __restrict__ lnbv,
    float* __restrict__ Cf, ushort* __restrict__ Cb,
    int M, int NO, int K)
{
  __shared__ ushort As[2][BM * BK];
  __shared__ ushort Ws[2][BN * BK];
  __shared__ float lnred[(FLAGS & 8) ? 512 : 4];

  const int tid = threadIdx.x;
  const int wv = tid >> 6, ln = tid & 63;
  const int bm = blockIdx.y * BM, bn = blockIdx.x * BN;
  const int wrow = (wv >> 1) * 64, wcol = (wv & 1) * 64;
  const int o_base = wv * 1024 + ln * 16;

  auto STG = [&](int kidx, int b) {
    #pragma unroll
    for (int is = 0; is < 4; ++is) {
      int o = is * 4096 + o_base;
      int row = o >> 7;
      int c = ((o >> 4) & 7) ^ (row & 7);
      int gm = min(bm + row, M - 1);
      const ushort* sA = A + (size_t)gm * K + kidx * BK + c * 8;
      __builtin_amdgcn_global_load_lds(
          (const __attribute__((address_space(1))) void*)sA,
          (__attribute__((address_space(3))) void*)((char*)As[b] + is * 4096 + wv * 1024),
          16, 0, 0);
      int gn = bn + row;
      const ushort* sW = W + (size_t)gn * K + kidx * BK + c * 8;
      __builtin_amdgcn_global_load_lds(
          (const __attribute__((address_space(1))) void*)sW,
          (__attribute__((address_space(3))) void*)((char*)Ws[b] + is * 4096 + wv * 1024),
          16, 0, 0);
    }
  };

  f32x4 acc[4][4] = {};
  const int KT = K >> 6;
  STG(0, 0);
  __syncthreads();
  int buf = 0;
  for (int i = 0; i < KT; ++i) {
    if (i + 1 < KT) STG(i + 1, buf ^ 1);
    const char* AsB = (const char*)As[buf];
    const char* WsB = (const char*)Ws[buf];
    #pragma unroll
    for (int kk = 0; kk < 2; ++kk) {
      bf16x8 af[4], bfr[4];
      #pragma unroll
      for (int m = 0; m < 4; ++m) {
        int r = wrow + m * 16 + (ln & 15);
        int c = kk * 4 + (ln >> 4);
        af[m] = *reinterpret_cast<const bf16x8*>(AsB + r * 128 + ((c ^ (r & 7)) << 4));
      }
      #pragma unroll
      for (int n = 0; n < 4; ++n) {
        int r = wcol + n * 16 + (ln & 15);
        int c = kk * 4 + (ln >> 4);
        bfr[n] = *reinterpret_cast<const bf16x8*>(WsB + r * 128 + ((c ^ (r & 7)) << 4));
      }
      #pragma unroll
      for (int m = 0; m < 4; ++m)
        #pragma unroll
        for (int n = 0; n < 4; ++n)
          acc[m][n] = __builtin_amdgcn_mfma_f32_16x16x32_bf16(af[m], bfr[n], acc[m][n], 0, 0, 0);
    }
    __syncthreads();
    buf ^= 1;
  }

  if constexpr ((FLAGS & 8) != 0) {
    #pragma unroll
    for (int m = 0; m < 4; ++m)
      #pragma unroll
      for (int n = 0; n < 4; ++n) {
        int gc = wcol + n * 16 + (ln & 15);
        float bsv = (FLAGS & 1) ? bias[gc] : 0.f;
        #pragma unroll
        for (int r = 0; r < 4; ++r) {
          int gr = bm + wrow + m * 16 + (ln >> 4) * 4 + r;
          float v = acc[m][n][r] + bsv;
          if (FLAGS & 2) v = fmaxf(v, 0.f);
          if (FLAGS & 4) v += res[(size_t)min(gr, M - 1) * 128 + gc];
          acc[m][n][r] = v;
        }
      }
    #pragma unroll
    for (int m = 0; m < 4; ++m)
      #pragma unroll
      for (int r = 0; r < 4; ++r) {
        float sm = acc[m][0][r] + acc[m][1][r] + acc[m][2][r] + acc[m][3][r];
        float sq = acc[m][0][r] * acc[m][0][r] + acc[m][1][r] * acc[m][1][r]
                 + acc[m][2][r] * acc[m][2][r] + acc[m][3][r] * acc[m][3][r];
        #pragma unroll
        for (int msk = 1; msk <= 8; msk <<= 1) {
          sm += __shfl_xor(sm, msk);
          sq += __shfl_xor(sq, msk);
        }
        if ((ln & 15) == 0) {
          int row = wrow + m * 16 + (ln >> 4) * 4 + r;
          lnred[row * 4 + (wv & 1) * 2]     = sm;
          lnred[row * 4 + (wv & 1) * 2 + 1] = sq;
        }
      }
    __syncthreads();
    #pragma unroll
    for (int m = 0; m < 4; ++m)
      #pragma unroll
      for (int r = 0; r < 4; ++r) {
        int row = wrow + m * 16 + (ln >> 4) * 4 + r;
        int gr = bm + row;
        float sm = lnred[row * 4] + lnred[row * 4 + 2];
        float sq = lnred[row * 4 + 1] + lnred[row * 4 + 3];
        float mu = sm * (1.f / 128.f);
        float var = fmaxf(sq * (1.f / 128.f) - mu * mu, 0.f);
        float rstd = rsqrtf(var + LN_EPS);
        if (gr < M) {
          #pragma unroll
          for (int n = 0; n < 4; ++n) {
            int gc = wcol + n * 16 + (ln & 15);
            float y = (acc[m][n][r] - mu) * rstd * lng[gc] + lnbv[gc];
            if (OUTF) Cf[(size_t)gr * 128 + gc] = y;
            if (OUTB) Cb[(size_t)gr * 128 + gc] = f2b(y);
          }
        }
      }
  } else {
    #pragma unroll
    for (int m = 0; m < 4; ++m) {
      int gr0 = bm + wrow + m * 16 + (ln >> 4) * 4;
      #pragma unroll
      for (int n = 0; n < 4; ++n) {
        int gc = bn + wcol + n * 16 + (ln & 15);
        float bsv = (FLAGS & 1) ? bias[gc] : 0.f;
        #pragma unroll
        for (int r = 0; r < 4; ++r) {
          int gr = gr0 + r;
          if (gr >= M) continue;
          float v = acc[m][n][r] + bsv;
          if (FLAGS & 2) v = fmaxf(v, 0.f);
          if (FLAGS & 4) v += res[(size_t)gr * NO + gc];
          if (OUTF) Cf[(size_t)gr * NO + gc] = v;
          if (OUTB) Cb[(size_t)gr * NO + gc] = f2b(v);
        }
      }
    }
  }
}

// ---------------- edge-softmax attention: fixed-max (scores clamped to ±5) ----
// softmax is shift-invariant: use C=5 so w=exp(u-5) in [e^-10, 1]. No running
// max, no rescale; group merge = plain sum. 8 groups x 8 lanes, lane = head.
__global__ __launch_bounds__(256) void k_attn(
    const ushort* __restrict__ q, const ushort* __restrict__ kv,
    const int* __restrict__ off, const int* __restrict__ csr,
    ushort* __restrict__ sav, int n)
{
  int node = blockIdx.x * 4 + (threadIdx.x >> 6);
  int lane = threadIdx.x & 63;
  if (node >= n) return;
  const int g = lane >> 3, sl = lane & 7;

  const ushort* qr = q + (size_t)node * 128 + sl * 16;
  uint4 qw0 = *reinterpret_cast<const uint4*>(qr);
  uint4 qw1 = *reinterpret_cast<const uint4*>(qr + 8);
  float qv[16];
  unpack8w(qw0, qv); unpack8w(qw1, qv + 8);

  int b = off[node], e = off[node + 1];
  float s = 0.f;
  float a[16] = {};
  int nIt = (e - b + 7) >> 3;
  int idx = b + g;
  int sn = (b < e) ? csr[min(idx, e - 1)] : 0;

  for (int i = 0; i < nIt; ++i) {
    bool act = idx < e;
    const ushort* kr = kv + (size_t)sn * 256 + sl * 16;
    uint4 kw0 = *reinterpret_cast<const uint4*>(kr);
    uint4 kw1 = *reinterpret_cast<const uint4*>(kr + 8);
    uint4 vw0 = *reinterpret_cast<const uint4*>(kr + 128);
    uint4 vw1 = *reinterpret_cast<const uint4*>(kr + 136);
    idx += 8;
    if (i + 1 < nIt) sn = csr[min(idx, e - 1)];

    float kk[16];
    unpack8w(kw0, kk); unpack8w(kw1, kk + 8);
    float p = 0.f;
    #pragma unroll
    for (int j = 0; j < 16; ++j) p = fmaf(qv[j], kk[j], p);
    float u = fminf(fmaxf(p * 0.25f, -CLAMP_V), CLAMP_V);
    float w = __expf(u - CLAMP_V);
    w = act ? w : 0.f;
    s += w;
    float vvv[16];
    unpack8w(vw0, vvv); unpack8w(vw1, vvv + 8);
    #pragma unroll
    for (int j = 0; j < 16; ++j) a[j] = fmaf(w, vvv[j], a[j]);
  }

  #pragma unroll
  for (int msk = 8; msk <= 32; msk <<= 1) {
    s += __shfl_xor(s, msk);
    #pragma unroll
    for (int j = 0; j < 16; ++j) a[j] += __shfl_xor(a[j], msk);
  }

  float inv = (s > 0.f) ? 1.f / s : 0.f;
  if (g == 0) {
    uint w[8];
    #pragma unroll
    for (int j = 0; j < 8; ++j)
      w[j] = (uint)f2b(a[2 * j] * inv) | ((uint)f2b(a[2 * j + 1] * inv) << 16);
    ushort* outp = sav + (size_t)node * 128 + sl * 16;
    uint4 o0 = {w[0], w[1], w[2], w[3]};
    uint4 o1 = {w[4], w[5], w[6], w[7]};
    *reinterpret_cast<uint4*>(outp) = o0;
    *reinterpret_cast<uint4*>(outp + 8) = o1;
  }
}

extern "C" void kernel_launch(void* const* d_in, const int* in_sizes, int n_in,
                              void* d_out, int out_size, void* d_ws, size_t ws_size,
                              hipStream_t stream)
{
  const float* feat = (const float*)d_in[0];
  const int*   src  = (const int*)d_in[1];
  const int*   dst  = (const int*)d_in[2];
  const float* Wq   = (const float*)d_in[3];
  const float* Wk   = (const float*)d_in[4];
  const float* Wv   = (const float*)d_in[5];
  const float* Wo   = (const float*)d_in[6];
  const float* ln1g = (const float*)d_in[7];
  const float* ln1b = (const float*)d_in[8];
  const float* W1   = (const float*)d_in[9];
  const float* b1   = (const float*)d_in[10];
  const float* W2   = (const float*)d_in[11];
  const float* b2   = (const float*)d_in[12];
  const float* ln2g = (const float*)d_in[13];
  const float* ln2b = (const float*)d_in[14];
  float* out = (float*)d_out;

  const int N = in_sizes[0] / DM;
  const int E = in_sizes[1];
  const size_t NB = (size_t)N;

  char* wsb = (char*)d_ws;
  ushort* q_bf    = (ushort*)wsb;
  ushort* kv_bf   = (ushort*)(wsb + NB * 256);
  ushort* sav_bf  = (ushort*)(wsb + NB * 768);
  ushort* mid_bf  = (ushort*)wsb;
  float*  h1      = (float*)(wsb + NB * 1024);
  ushort* h1b     = (ushort*)(wsb + NB * 1536);
  ushort* feat_bf = (ushort*)(wsb + NB * 1792);
  ushort* wbf     = (ushort*)(wsb + NB * 2048);
  ushort* wqkv_bf = wbf;
  ushort* wo_bf   = wbf + 49152;
  ushort* w1_bf   = wbf + 65536;
  ushort* w2_bf   = wbf + 131072;
  int* ib  = (int*)(wbf + 196608);
  int* deg = ib;
  int* cur = ib + N;
  int* off = ib + 2 * N;
  int* csr = ib + 3 * N + 1;
  int* bsum = csr + E;

  hipMemsetAsync(deg, 0, 2 * (size_t)N * sizeof(int), stream);

  int nf = N * DM;
  k_cast<<<(nf / 4 + 255) / 256, 256, 0, stream>>>(feat, feat_bf, nf);
  k_castw<<<192, 256, 0, stream>>>(Wq, Wk, Wv, Wo, W1, W2, wbf);

  int eb = (E + 255) / 256;
  int nbk = (N + SC_EPB - 1) / SC_EPB;
  k_count<<<eb, 256, 0, stream>>>(dst, deg, E);
  k_scan1<<<nbk, 256, 0, stream>>>(deg, off, bsum, N);
  k_scan2<<<1, 256, 0, stream>>>(bsum, nbk);
  k_scan3<<<nbk, 256, 0, stream>>>(off, bsum, N, E);
  k_scatter<<<eb, 256, 0, stream>>>(src, dst, off, cur, csr, E);

  int nb4 = (N + 3) / 4;
  const int nT = (N + 127) / 128;   // 313

  // qkv: one dispatch, split output (q_bf | kv_bf). grid x=3 (q,k,v panels)
  {
    int S = (nT + 3) / 4;           // T=4
    k_mmS<0, true, false, true><<<dim3(3, S), 512, 0, stream>>>(
        feat_bf, wqkv_bf, nullptr, nullptr, nullptr, nullptr,
        nullptr, q_bf, kv_bf, N, 0);
  }

  k_attn<<<nb4, 256, 0, stream>>>(q_bf, kv_bf, off, csr, sav_bf, N);

  // h1 = LN1(sav @ Wo^T + feat) -> h1 f32 + h1b bf16
  {
    int S = (nT + 1) / 2;           // T=2
    k_mmS<4 | 8, false, true, true><<<dim3(1, S), 512, 0, stream>>>(
        sav_bf, wo_bf, nullptr, feat, ln1g, ln1b, h1, h1b, nullptr, N, 128);
  }

  // mid = relu(h1 @ W1^T + b1)
  {
    int S = (nT + 4) / 5;           // T=5
    k_mmS<1 | 2, false, false, true><<<dim3(4, S), 512, 0, stream>>>(
        h1b, w1_bf, b1, nullptr, nullptr, nullptr,
        nullptr, mid_bf, nullptr, N, DFF);
  }

  // out = LN2(mid @ W2^T + b2 + h1), K=512 double-buffered
  k_mm2<1 | 4 | 8, true, false><<<dim3(1, nT), 256, 0, stream>>>(
      mid_bf, w2_bf, b2, h1, ln2g, ln2b, out, nullptr, N, DM, DFF);
}